// Round 1
// baseline (3991.771 us; speedup 1.0000x reference)
//
#include <hip/hip_runtime.h>
#include <math.h>

#define SEQ    720
#define PRED   720
#define CH     321
#define FCUT   200
#define FOUT   400
#define NBATCH 256
#define NTOT   1440
#define KR     400   // stacked rfft rows: 200 cos + 200 (-sin)
#define MC     800   // stacked mixed rows: 400 real + 400 imag

static __device__ __forceinline__ float4 f4zero() { return make_float4(0.f, 0.f, 0.f, 0.f); }

// ---------------- init: DFT basis matrices ----------------
// Dmat[m][t], m<200: cos(2*pi*m*t/720) ; m in [200,400): -sin(2*pi*(m-200)*t/720)
__global__ void init_dmat(float* __restrict__ D) {
    int i = blockIdx.x * 256 + threadIdx.x;
    if (i >= KR * SEQ) return;
    int fp = i / SEQ, t = i % SEQ;
    int f = (fp < FCUT) ? fp : (fp - FCUT);
    int p = (f * t) % SEQ;
    float ang = (float)p * (6.28318530717958647692f / (float)SEQ);
    D[i] = (fp < FCUT) ? cosf(ang) : -sinf(ang);
}

// Gmat[t'][k], t = t'+720 (last 720 of 1440), scale s = LENGTH_RATIO/NTOT = 2/1440.
// k<400 (real part coeff):  k==0 ? s : 2*s*cos(2*pi*k*t/1440)
// k>=400 (imag part coeff): k'==0 ? 0 : -2*s*sin(2*pi*k'*t/1440)   (irfft ignores Im of DC bin)
__global__ void init_gmat(float* __restrict__ G) {
    int i = blockIdx.x * 256 + threadIdx.x;
    if (i >= SEQ * MC) return;
    int tp = i / MC, kp = i % MC;
    int t = tp + PRED;
    int k = (kp < FOUT) ? kp : (kp - FOUT);
    int p = (k * t) % NTOT;
    float ang = (float)p * (6.28318530717958647692f / (float)NTOT);
    const float s = 2.0f / (float)NTOT;
    float v;
    if (kp < FOUT) v = (k == 0) ? s : (2.0f * s * cosf(ang));
    else           v = (k == 0) ? 0.0f : (-2.0f * s * sinf(ang));
    G[i] = v;
}

// ---------------- stats: mean / stdev per (b,c) ----------------
__global__ void stats_kernel(const float* __restrict__ x,
                             float* __restrict__ mean_bc,
                             float* __restrict__ rstd_bc,
                             float* __restrict__ stdev_bc) {
    int i = blockIdx.x * 256 + threadIdx.x;
    if (i >= NBATCH * CH) return;
    int b = i / CH, c = i % CH;
    const float* p = x + (size_t)b * SEQ * CH + c;
    float s = 0.f, ss = 0.f;
    for (int t = 0; t < SEQ; ++t) {
        float v = p[(size_t)t * CH];
        s += v; ss += v * v;
    }
    float mean = s / (float)SEQ;
    float var = fmaxf((ss - s * mean) / (float)(SEQ - 1), 0.f);
    float st = sqrtf(var + 1e-5f);
    mean_bc[i] = mean;
    stdev_bc[i] = st;
    rstd_bc[i] = 1.0f / st;
}

// ---------------- GEMM B: rfft.  per-b: (400x720)x(720x321) -> Xbuf[b'][400][321] ----------------
__global__ __launch_bounds__(256)
void gemm_rfft(const float* __restrict__ Dm, const float* __restrict__ x,
               const float* __restrict__ mean_bc, const float* __restrict__ rstd_bc,
               float* __restrict__ Xbuf, int b0) {
    const int bl = blockIdx.z;
    const int b = b0 + bl;
    const int m0 = blockIdx.x * 64;
    const int n0 = blockIdx.y * 64;
    const int tid = threadIdx.x;
    const int tm = (tid >> 4) * 4;
    const int tn = (tid & 15) * 4;
    const int mA = tid >> 2;
    const int kA = (tid & 3) * 4;
    const int kB = tid >> 4;
    const int nB = (tid & 15) * 4;

    __shared__ float As[16][64];
    __shared__ float Bs[16][64];

    float acc[4][4];
#pragma unroll
    for (int i = 0; i < 4; ++i)
#pragma unroll
        for (int j = 0; j < 4; ++j) acc[i][j] = 0.f;

    float mnorm[4], rnorm[4];
#pragma unroll
    for (int j = 0; j < 4; ++j) {
        int gn = n0 + nB + j;
        mnorm[j] = (gn < CH) ? mean_bc[b * CH + gn] : 0.f;
        rnorm[j] = (gn < CH) ? rstd_bc[b * CH + gn] : 0.f;
    }
    const float* xb = x + (size_t)b * SEQ * CH;

    for (int k0 = 0; k0 < SEQ; k0 += 16) {
        float4 av = f4zero();
        int gm = m0 + mA;
        if (gm < KR) av = *(const float4*)(Dm + (size_t)gm * SEQ + k0 + kA);
        As[kA + 0][mA] = av.x; As[kA + 1][mA] = av.y;
        As[kA + 2][mA] = av.z; As[kA + 3][mA] = av.w;

        int gk = k0 + kB;
#pragma unroll
        for (int j = 0; j < 4; ++j) {
            int gn = n0 + nB + j;
            float v = 0.f;
            if (gn < CH) v = (xb[(size_t)gk * CH + gn] - mnorm[j]) * rnorm[j];
            Bs[kB][nB + j] = v;
        }
        __syncthreads();
#pragma unroll
        for (int kk = 0; kk < 16; ++kk) {
            float4 a4 = *(const float4*)&As[kk][tm];
            float4 b4 = *(const float4*)&Bs[kk][tn];
            float aa[4] = {a4.x, a4.y, a4.z, a4.w};
            float bb[4] = {b4.x, b4.y, b4.z, b4.w};
#pragma unroll
            for (int i = 0; i < 4; ++i)
#pragma unroll
                for (int j = 0; j < 4; ++j)
                    acc[i][j] = fmaf(aa[i], bb[j], acc[i][j]);
        }
        __syncthreads();
    }

    float* outp = Xbuf + (size_t)bl * KR * CH;
#pragma unroll
    for (int i = 0; i < 4; ++i) {
        int m = m0 + tm + i;
        if (m >= KR) continue;
#pragma unroll
        for (int j = 0; j < 4; ++j) {
            int n = n0 + tn + j;
            if (n < CH) outp[(size_t)m * CH + n] = acc[i][j];
        }
    }
}

// ---------------- T1: Xbuf[b'][f][c] -> XT[c][f][b'] ----------------
__global__ void transpose_bc(const float* __restrict__ in, float* __restrict__ out, int Bc) {
    __shared__ float tile[32][33];
    int f = blockIdx.x;
    int c0 = blockIdx.y * 32, b0 = blockIdx.z * 32;
    int tx = threadIdx.x, ty = threadIdx.y;
#pragma unroll
    for (int j = 0; j < 4; ++j) {
        int bb = b0 + ty + j * 8, cc = c0 + tx;
        if (bb < Bc && cc < CH)
            tile[ty + j * 8][tx] = in[(size_t)bb * KR * CH + (size_t)f * CH + cc];
    }
    __syncthreads();
#pragma unroll
    for (int j = 0; j < 4; ++j) {
        int cc = c0 + ty + j * 8, bb = b0 + tx;
        if (cc < CH && bb < Bc)
            out[(size_t)cc * KR * Bc + (size_t)f * Bc + bb] = tile[tx][ty + j * 8];
    }
}

// ---------------- GEMM C: channel mix. per-c: (800x400)x(400xBc) + bias -> F[c][800][Bc] ----------------
__global__ __launch_bounds__(256)
void gemm_mix(const float* __restrict__ Wr, const float* __restrict__ Wi,
              const float* __restrict__ brv, const float* __restrict__ biv,
              const float* __restrict__ XT, float* __restrict__ F, int Bc) {
    const int c = blockIdx.z;
    const int m0 = blockIdx.x * 64;
    const int n0 = blockIdx.y * 64;
    const int tid = threadIdx.x;
    const int tm = (tid >> 4) * 4;
    const int tn = (tid & 15) * 4;
    const int mA = tid >> 2;
    const int kA = (tid & 3) * 4;
    const int kB = tid >> 4;
    const int nB = (tid & 15) * 4;

    __shared__ float As[16][64];
    __shared__ float Bs[16][64];

    float acc[4][4];
#pragma unroll
    for (int i = 0; i < 4; ++i)
#pragma unroll
        for (int j = 0; j < 4; ++j) acc[i][j] = 0.f;

    const float* wrc = Wr + (size_t)c * FOUT * FCUT;
    const float* wic = Wi + (size_t)c * FOUT * FCUT;
    const float* Bmat = XT + (size_t)c * KR * Bc;

    for (int k0 = 0; k0 < KR; k0 += 16) {
        float4 av = f4zero();
        int gm = m0 + mA;
        int gk = k0 + kA;
        if (gm < MC) {
            bool hi = (gm >= FOUT);
            int o = hi ? (gm - FOUT) : gm;
            bool kb = (gk >= FCUT);
            int k2 = kb ? (gk - FCUT) : gk;
            const float* basep = (hi != kb) ? wic : wrc;
            av = *(const float4*)(basep + (size_t)o * FCUT + k2);
            if (!hi && kb) { av.x = -av.x; av.y = -av.y; av.z = -av.z; av.w = -av.w; }
        }
        As[kA + 0][mA] = av.x; As[kA + 1][mA] = av.y;
        As[kA + 2][mA] = av.z; As[kA + 3][mA] = av.w;

        int gkB = k0 + kB;
#pragma unroll
        for (int j = 0; j < 4; ++j) {
            int gn = n0 + nB + j;
            Bs[kB][nB + j] = (gn < Bc) ? Bmat[(size_t)gkB * Bc + gn] : 0.f;
        }
        __syncthreads();
#pragma unroll
        for (int kk = 0; kk < 16; ++kk) {
            float4 a4 = *(const float4*)&As[kk][tm];
            float4 b4 = *(const float4*)&Bs[kk][tn];
            float aa[4] = {a4.x, a4.y, a4.z, a4.w};
            float bb[4] = {b4.x, b4.y, b4.z, b4.w};
#pragma unroll
            for (int i = 0; i < 4; ++i)
#pragma unroll
                for (int j = 0; j < 4; ++j)
                    acc[i][j] = fmaf(aa[i], bb[j], acc[i][j]);
        }
        __syncthreads();
    }

#pragma unroll
    for (int i = 0; i < 4; ++i) {
        int m = m0 + tm + i;
        if (m >= MC) continue;
        float bias = (m < FOUT) ? brv[(size_t)c * FOUT + m] : biv[(size_t)c * FOUT + (m - FOUT)];
#pragma unroll
        for (int j = 0; j < 4; ++j) {
            int n = n0 + tn + j;
            if (n < Bc) F[(size_t)c * MC * Bc + (size_t)m * Bc + n] = acc[i][j] + bias;
        }
    }
}

// ---------------- GEMM D: irfft. per-c: (720x800)x(800xBc) -> outT[c][720][Bc] ----------------
__global__ __launch_bounds__(256)
void gemm_irfft(const float* __restrict__ G, const float* __restrict__ Fm,
                float* __restrict__ outT, int Bc) {
    const int c = blockIdx.z;
    const int m0 = blockIdx.x * 64;
    const int n0 = blockIdx.y * 64;
    const int tid = threadIdx.x;
    const int tm = (tid >> 4) * 4;
    const int tn = (tid & 15) * 4;
    const int mA = tid >> 2;
    const int kA = (tid & 3) * 4;
    const int kB = tid >> 4;
    const int nB = (tid & 15) * 4;

    __shared__ float As[16][64];
    __shared__ float Bs[16][64];

    float acc[4][4];
#pragma unroll
    for (int i = 0; i < 4; ++i)
#pragma unroll
        for (int j = 0; j < 4; ++j) acc[i][j] = 0.f;

    const float* Bmat = Fm + (size_t)c * MC * Bc;

    for (int k0 = 0; k0 < MC; k0 += 16) {
        float4 av = f4zero();
        int gm = m0 + mA;
        if (gm < SEQ) av = *(const float4*)(G + (size_t)gm * MC + k0 + kA);
        As[kA + 0][mA] = av.x; As[kA + 1][mA] = av.y;
        As[kA + 2][mA] = av.z; As[kA + 3][mA] = av.w;

        int gk = k0 + kB;
#pragma unroll
        for (int j = 0; j < 4; ++j) {
            int gn = n0 + nB + j;
            Bs[kB][nB + j] = (gn < Bc) ? Bmat[(size_t)gk * Bc + gn] : 0.f;
        }
        __syncthreads();
#pragma unroll
        for (int kk = 0; kk < 16; ++kk) {
            float4 a4 = *(const float4*)&As[kk][tm];
            float4 b4 = *(const float4*)&Bs[kk][tn];
            float aa[4] = {a4.x, a4.y, a4.z, a4.w};
            float bb[4] = {b4.x, b4.y, b4.z, b4.w};
#pragma unroll
            for (int i = 0; i < 4; ++i)
#pragma unroll
                for (int j = 0; j < 4; ++j)
                    acc[i][j] = fmaf(aa[i], bb[j], acc[i][j]);
        }
        __syncthreads();
    }

#pragma unroll
    for (int i = 0; i < 4; ++i) {
        int m = m0 + tm + i;
        if (m >= SEQ) continue;
#pragma unroll
        for (int j = 0; j < 4; ++j) {
            int n = n0 + tn + j;
            if (n < Bc) outT[(size_t)c * SEQ * Bc + (size_t)m * Bc + n] = acc[i][j];
        }
    }
}

// ---------------- T3: outT[c][t][b'] -> out[b0+b'][t][c], fused de-standardize ----------------
__global__ void transpose_out(const float* __restrict__ outT,
                              const float* __restrict__ mean_bc,
                              const float* __restrict__ stdev_bc,
                              float* __restrict__ out, int b0, int Bc) {
    __shared__ float tile[32][33];
    int t = blockIdx.x;
    int c0 = blockIdx.y * 32, bb0 = blockIdx.z * 32;
    int tx = threadIdx.x, ty = threadIdx.y;
#pragma unroll
    for (int j = 0; j < 4; ++j) {
        int cc = c0 + ty + j * 8, bl = bb0 + tx;
        if (cc < CH && bl < Bc)
            tile[ty + j * 8][tx] = outT[(size_t)cc * SEQ * Bc + (size_t)t * Bc + bl];
    }
    __syncthreads();
#pragma unroll
    for (int j = 0; j < 4; ++j) {
        int cc = c0 + tx, bl = bb0 + ty + j * 8;
        if (cc < CH && bl < Bc) {
            int b = b0 + bl;
            size_t si = (size_t)b * CH + cc;
            out[(size_t)b * SEQ * CH + (size_t)t * CH + cc] =
                tile[tx][ty + j * 8] * stdev_bc[si] + mean_bc[si];
        }
    }
}

// ---------------- launch ----------------
extern "C" void kernel_launch(void* const* d_in, const int* in_sizes, int n_in,
                              void* d_out, int out_size, void* d_ws, size_t ws_size,
                              hipStream_t stream) {
    const float* x_enc = (const float*)d_in[0];
    const float* Wr = (const float*)d_in[4];
    const float* Wi = (const float*)d_in[5];
    const float* br = (const float*)d_in[6];
    const float* bi = (const float*)d_in[7];
    float* out = (float*)d_out;

    auto al = [](size_t x) { return (x + 63) & ~(size_t)63; };  // 256B-align (floats)
    const size_t fixedf = al((size_t)KR * SEQ) + al((size_t)SEQ * MC) + 3 * al((size_t)NBATCH * CH);

    // pick largest batch chunk Bc that fits ws
    int Bc = NBATCH;
    while (Bc > 1) {
        size_t perb = al((size_t)Bc * KR * CH) * 2 + al((size_t)Bc * MC * CH) + al((size_t)Bc * SEQ * CH);
        if ((fixedf + perb) * sizeof(float) <= ws_size) break;
        Bc >>= 1;
    }

    float* ws = (float*)d_ws;
    size_t oD = 0;
    size_t oG = oD + al((size_t)KR * SEQ);
    size_t oMean = oG + al((size_t)SEQ * MC);
    size_t oRstd = oMean + al((size_t)NBATCH * CH);
    size_t oStd = oRstd + al((size_t)NBATCH * CH);
    size_t oX = oStd + al((size_t)NBATCH * CH);
    size_t oXT = oX + al((size_t)Bc * KR * CH);
    size_t oF = oXT + al((size_t)Bc * KR * CH);
    size_t oOT = oF + al((size_t)Bc * MC * CH);

    init_dmat<<<(KR * SEQ + 255) / 256, 256, 0, stream>>>(ws + oD);
    init_gmat<<<(SEQ * MC + 255) / 256, 256, 0, stream>>>(ws + oG);
    stats_kernel<<<(NBATCH * CH + 255) / 256, 256, 0, stream>>>(x_enc, ws + oMean, ws + oRstd, ws + oStd);

    const int nch = NBATCH / Bc;
    for (int ci = 0; ci < nch; ++ci) {
        int b0 = ci * Bc;
        dim3 gB((KR + 63) / 64, (CH + 63) / 64, Bc);
        gemm_rfft<<<gB, 256, 0, stream>>>(ws + oD, x_enc, ws + oMean, ws + oRstd, ws + oX, b0);

        dim3 gT1(KR, (CH + 31) / 32, (Bc + 31) / 32);
        transpose_bc<<<gT1, dim3(32, 8), 0, stream>>>(ws + oX, ws + oXT, Bc);

        dim3 gC((MC + 63) / 64, (Bc + 63) / 64, CH);
        gemm_mix<<<gC, 256, 0, stream>>>(Wr, Wi, br, bi, ws + oXT, ws + oF, Bc);

        dim3 gD((SEQ + 63) / 64, (Bc + 63) / 64, CH);
        gemm_irfft<<<gD, 256, 0, stream>>>(ws + oG, ws + oF, ws + oOT, Bc);

        dim3 gT3(SEQ, (CH + 31) / 32, (Bc + 31) / 32);
        transpose_out<<<gT3, dim3(32, 8), 0, stream>>>(ws + oOT, ws + oMean, ws + oStd, out, b0, Bc);
    }
}